// Round 6
// baseline (127.705 us; speedup 1.0000x reference)
//
#include <hip/hip_runtime.h>

// 22-qubit QAOA state-vector sim. Register/shfl/LDS-transpose butterflies.
// Butterfly c = cb*c + i*sb*partner is symmetric -> run each stage where the
// partner lives. fp16 state in HBM only; all math f32.
//   K1: init + phase1 + layer1 bits 0-12   (contiguous tiles)
//   K2: layer1 bits 13-21 + phase2 + layer2 bits 13-21  (strided, GRP=32)
//   K3: layer2 bits 0-12 + fused |c|^2*hS reduce -> atomicAdd
// R6: K1/K3 rebuilt for OCCUPANCY (R4 showed DS/HBM not binding -> latency):
//   R=8, TPB=1024, launch_bounds(1024,8) targeting <=64 VGPR = 8 waves/SIMD,
//   f32 shfl (no cvt VALU in stages), fp16 only at HBM boundary.

#define NTOT    (1u << 22)
#define LO_BITS 13
#define HI_BITS 9
#define LO      (1u << LO_BITS)   // 8192
#define HI      (1u << HI_BITS)   // 512
#define GRP     32                // lo-columns per K2 block (128B segments)
#define TPB1    1024              // K1/K3 block
#define TPB2    1024              // K2 block
#define R8      8                 // elements/thread in K1/K3
#define R       16                // elements/thread in K2

typedef __fp16 h2_t __attribute__((ext_vector_type(2)));
union PkU { unsigned u; h2_t h; };

__device__ __forceinline__ unsigned pk(float x, float y) {
    PkU p; p.h = __builtin_amdgcn_cvt_pkrtz(x, y); return p.u;
}
__device__ __forceinline__ float2 unpk(unsigned v) {
    PkU p; p.u = v; return make_float2((float)p.h.x, (float)p.h.y);
}

// register butterfly on register-index bit MASK (f32), NR elements
#define REGSTAGE_N(NR, MASK, CB, SB) {                            \
    _Pragma("unroll")                                             \
    for (int r0 = 0; r0 < (NR); ++r0) {                           \
        if ((r0 & (MASK)) == 0) {                                 \
            const int r1 = r0 | (MASK);                           \
            float t0r = re[r0], t0i = im[r0];                     \
            float t1r = re[r1], t1i = im[r1];                     \
            re[r0] = (CB) * t0r - (SB) * t1i;                     \
            im[r0] = (CB) * t0i + (SB) * t1r;                     \
            re[r1] = (CB) * t1r - (SB) * t0i;                     \
            im[r1] = (CB) * t1i + (SB) * t0r;                     \
        } } }

// f32 cross-lane butterfly (2 DS ops, zero cvt VALU)
#define SHFLSTAGE_N(NR, MASK, CB, SB) {                           \
    _Pragma("unroll")                                             \
    for (int r = 0; r < (NR); ++r) {                              \
        float tr = re[r], ti = im[r];                             \
        float pr = __shfl_xor(tr, (MASK), 64);                    \
        float pi = __shfl_xor(ti, (MASK), 64);                    \
        re[r] = (CB) * tr - (SB) * pi;                            \
        im[r] = (CB) * ti + (SB) * pr;                            \
    } }

// fp16-packed shfl for K2 (kept from R5 — K2 frozen this round)
#define SHFLSTAGE(MASK, CB, SB) {                                 \
    _Pragma("unroll")                                             \
    for (int r = 0; r < R; ++r) {                                 \
        unsigned pv = (unsigned)__shfl_xor((int)pk(re[r], im[r]), (MASK), 64); \
        float2 p = unpk(pv);                                      \
        float tr = re[r], ti = im[r];                             \
        re[r] = (CB) * tr - (SB) * p.y;                           \
        im[r] = (CB) * ti + (SB) * p.x;                           \
    } }
#define REGSTAGE(MASK, CB, SB) REGSTAGE_N(R, MASK, CB, SB)

// ---------------- K1: init + phase1 + layer-1 bits 0-12 ----------------
// TPB=1024, R=8. elem (mapping A): i = r*1024 + t -> bits0-5 lane, 6-9 wave, 10-12 r.
// Stages: REG bits 10-12; SHFL bits 0-5; T1 (wave bits 6-8 -> reg); REG bits
// 6-8; bit 9 via LDS exchange; store at mapping B.
__global__ __launch_bounds__(TPB1, 8) void k_init_low(
    const float* __restrict__ h, const float* __restrict__ gam,
    const float* __restrict__ bet, unsigned* __restrict__ st,
    float* __restrict__ out)
{
    __shared__ float2 sC[LO];   // 64 KB
    const float g1 = gam[0];
    const float cb = __cosf(bet[0]), sb = __sinf(bet[0]);
    const unsigned t = threadIdx.x, lane = t & 63u, w = t >> 6;
    const size_t base = (size_t)blockIdx.x * LO;
    float re[R8], im[R8];

    if (blockIdx.x == 0 && t == 0) out[0] = 0.f;   // K3 accumulates later

    #pragma unroll
    for (int r = 0; r < R8; ++r) {
        float s, c;
        __sincosf(g1 * h[base + (unsigned)r * TPB1 + t], &s, &c);
        re[r] = c * 0x1p-11f;
        im[r] = s * 0x1p-11f;
    }
    REGSTAGE_N(R8, 1, cb, sb)  REGSTAGE_N(R8, 2, cb, sb)  REGSTAGE_N(R8, 4, cb, sb) // bits 10-12
    SHFLSTAGE_N(R8, 1,  cb, sb) SHFLSTAGE_N(R8, 2,  cb, sb)   // bits 0,1
    SHFLSTAGE_N(R8, 4,  cb, sb) SHFLSTAGE_N(R8, 8,  cb, sb)   // bits 2,3
    SHFLSTAGE_N(R8, 16, cb, sb) SHFLSTAGE_N(R8, 32, cb, sb)   // bits 4,5
    // T1: A -> B.  B: j = lane | r<<6 | w3<<9 | (w&7)<<10
    #pragma unroll
    for (int r = 0; r < R8; ++r) sC[(unsigned)r * TPB1 + t] = make_float2(re[r], im[r]);
    __syncthreads();
    #pragma unroll
    for (int r = 0; r < R8; ++r) {
        unsigned j = lane | ((unsigned)r << 6) | ((w & 8u) << 6) | ((w & 7u) << 10);
        float2 v = sC[j]; re[r] = v.x; im[r] = v.y;
    }
    REGSTAGE_N(R8, 1, cb, sb)  REGSTAGE_N(R8, 2, cb, sb)  REGSTAGE_N(R8, 4, cb, sb) // bits 6-8
    // bit 9 via LDS exchange at mapping B (partner: j ^ 512)
    __syncthreads();   // WAR on sC
    #pragma unroll
    for (int r = 0; r < R8; ++r) {
        unsigned j = lane | ((unsigned)r << 6) | ((w & 8u) << 6) | ((w & 7u) << 10);
        sC[j] = make_float2(re[r], im[r]);
    }
    __syncthreads();
    #pragma unroll
    for (int r = 0; r < R8; ++r) {
        unsigned j = lane | ((unsigned)r << 6) | ((w & 8u) << 6) | ((w & 7u) << 10);
        float2 p = sC[j ^ 512u];
        float tr = re[r], ti = im[r];
        re[r] = cb * tr - sb * p.y;
        im[r] = cb * ti + sb * p.x;
        st[base + j] = pk(re[r], im[r]);
    }
}

// -------- K2: layer-1 bits 13-21 + phase2 + layer-2 bits 13-21 --------
// (unchanged from R5) TPB2=1024: lane = g(5 lo bits)|h0(hi bit0); w(4); r(4).
// mapping A: hi = h0 | w<<1 | r<<5 ; mapping B: hi = h0 | r<<1 | w<<5
__global__ __launch_bounds__(TPB2, 4) void k_high(
    const float* __restrict__ h, const float* __restrict__ gam,
    const float* __restrict__ bet, unsigned* __restrict__ st)
{
    __shared__ unsigned sC[GRP * HI];   // 16384 words, 64 KB
    const float g2  = gam[1];
    const float cb1 = __cosf(bet[0]), sb1 = __sinf(bet[0]);
    const float cb2 = __cosf(bet[1]), sb2 = __sinf(bet[1]);
    const unsigned t = threadIdx.x, lane = t & 63u, w = t >> 6;  // w: 0..15
    const unsigned g  = lane & 31u;   // lo offset within group (coalescing)
    const unsigned h0 = lane >> 5;    // hi bit 0
    const unsigned lo0 = blockIdx.x * GRP;
    float re[R], im[R];

    #pragma unroll
    for (int r = 0; r < R; ++r) {
        unsigned hi = h0 | (w << 1) | ((unsigned)r << 5);
        float2 v = unpk(st[(size_t)hi * LO + lo0 + g]);
        re[r] = v.x; im[r] = v.y;
    }
    REGSTAGE(1, cb1, sb1)  REGSTAGE(2, cb1, sb1)
    REGSTAGE(4, cb1, sb1)  REGSTAGE(8, cb1, sb1)   // hi bits 5-8
    SHFLSTAGE(32, cb1, sb1)                         // hi bit 0
    #pragma unroll
    for (int r = 0; r < R; ++r)
        sC[g | (h0 << 5) | (w << 6) | ((unsigned)r << 10)] = pk(re[r], im[r]);
    __syncthreads();
    #pragma unroll
    for (int r = 0; r < R; ++r) {
        float2 v = unpk(sC[g | (h0 << 5) | ((unsigned)r << 6) | (w << 10)]);
        re[r] = v.x; im[r] = v.y;
    }
    REGSTAGE(1, cb1, sb1)  REGSTAGE(2, cb1, sb1)
    REGSTAGE(4, cb1, sb1)  REGSTAGE(8, cb1, sb1)   // hi bits 1-4; layer1 done
    #pragma unroll
    for (int r = 0; r < R; ++r) {
        unsigned hi = h0 | ((unsigned)r << 1) | (w << 5);
        float s, c;
        __sincosf(g2 * h[(size_t)hi * LO + lo0 + g], &s, &c);
        float tr = re[r], ti = im[r];
        re[r] = tr * c - ti * s;
        im[r] = tr * s + ti * c;
    }
    REGSTAGE(1, cb2, sb2)  REGSTAGE(2, cb2, sb2)
    REGSTAGE(4, cb2, sb2)  REGSTAGE(8, cb2, sb2)   // hi bits 1-4
    SHFLSTAGE(32, cb2, sb2)                         // hi bit 0
    __syncthreads();
    #pragma unroll
    for (int r = 0; r < R; ++r)
        sC[g | (h0 << 5) | ((unsigned)r << 6) | (w << 10)] = pk(re[r], im[r]);
    __syncthreads();
    #pragma unroll
    for (int r = 0; r < R; ++r) {
        float2 v = unpk(sC[g | (h0 << 5) | (w << 6) | ((unsigned)r << 10)]);
        re[r] = v.x; im[r] = v.y;
    }
    REGSTAGE(1, cb2, sb2)  REGSTAGE(2, cb2, sb2)
    REGSTAGE(4, cb2, sb2)  REGSTAGE(8, cb2, sb2)   // hi bits 5-8; layer2 done
    #pragma unroll
    for (int r = 0; r < R; ++r) {
        unsigned hi = h0 | (w << 1) | ((unsigned)r << 5);
        st[(size_t)hi * LO + lo0 + g] = pk(re[r], im[r]);
    }
}

// -------- K3: layer-2 bits 0-12 + fused |c|^2 * hS -> atomicAdd --------
// Mirror of K1 with bet[1]; ends in reduction instead of store.
__global__ __launch_bounds__(TPB1, 8) void k_low2(
    const float* __restrict__ hS, const float* __restrict__ bet,
    const unsigned* __restrict__ st, float* __restrict__ out)
{
    __shared__ float2 sC[LO];            // 64 KB
    __shared__ float wsum[TPB1 / 64];
    const float cb = __cosf(bet[1]), sb = __sinf(bet[1]);
    const unsigned t = threadIdx.x, lane = t & 63u, w = t >> 6;
    const size_t base = (size_t)blockIdx.x * LO;
    float re[R8], im[R8];

    #pragma unroll
    for (int r = 0; r < R8; ++r) {
        float2 v = unpk(st[base + (unsigned)r * TPB1 + t]);
        re[r] = v.x; im[r] = v.y;
    }
    REGSTAGE_N(R8, 1, cb, sb)  REGSTAGE_N(R8, 2, cb, sb)  REGSTAGE_N(R8, 4, cb, sb)
    SHFLSTAGE_N(R8, 1,  cb, sb) SHFLSTAGE_N(R8, 2,  cb, sb)
    SHFLSTAGE_N(R8, 4,  cb, sb) SHFLSTAGE_N(R8, 8,  cb, sb)
    SHFLSTAGE_N(R8, 16, cb, sb) SHFLSTAGE_N(R8, 32, cb, sb)
    #pragma unroll
    for (int r = 0; r < R8; ++r) sC[(unsigned)r * TPB1 + t] = make_float2(re[r], im[r]);
    __syncthreads();
    #pragma unroll
    for (int r = 0; r < R8; ++r) {
        unsigned j = lane | ((unsigned)r << 6) | ((w & 8u) << 6) | ((w & 7u) << 10);
        float2 v = sC[j]; re[r] = v.x; im[r] = v.y;
    }
    REGSTAGE_N(R8, 1, cb, sb)  REGSTAGE_N(R8, 2, cb, sb)  REGSTAGE_N(R8, 4, cb, sb)
    __syncthreads();   // WAR on sC
    #pragma unroll
    for (int r = 0; r < R8; ++r) {
        unsigned j = lane | ((unsigned)r << 6) | ((w & 8u) << 6) | ((w & 7u) << 10);
        sC[j] = make_float2(re[r], im[r]);
    }
    __syncthreads();
    float acc = 0.f;
    #pragma unroll
    for (int r = 0; r < R8; ++r) {
        unsigned j = lane | ((unsigned)r << 6) | ((w & 8u) << 6) | ((w & 7u) << 10);
        float2 p = sC[j ^ 512u];
        float tr = cb * re[r] - sb * p.y;
        float ti = cb * im[r] + sb * p.x;
        acc = fmaf(tr * tr + ti * ti, hS[base + j], acc);
    }
    #pragma unroll
    for (int off = 32; off >= 1; off >>= 1)
        acc += __shfl_down(acc, off, 64);
    if (lane == 0) wsum[w] = acc;
    __syncthreads();
    if (t == 0) {
        float s = 0.f;
        #pragma unroll
        for (int i = 0; i < TPB1 / 64; ++i) s += wsum[i];
        unsafeAtomicAdd(out, s);   // native global_atomic_add_f32
    }
}

extern "C" void kernel_launch(void* const* d_in, const int* in_sizes, int n_in,
                              void* d_out, int out_size, void* d_ws, size_t ws_size,
                              hipStream_t stream)
{
    (void)in_sizes; (void)n_in; (void)out_size; (void)ws_size;
    const float* h   = (const float*)d_in[0];
    const float* hS  = (const float*)d_in[1];
    const float* gam = (const float*)d_in[2];
    const float* bet = (const float*)d_in[3];
    unsigned* st = (unsigned*)d_ws;       // 16 MB half2 state
    float* out   = (float*)d_out;

    k_init_low<<<dim3(NTOT / LO), dim3(TPB1), 0, stream>>>(h, gam, bet, st, out);
    k_high    <<<dim3(LO / GRP),  dim3(TPB2), 0, stream>>>(h, gam, bet, st);
    k_low2    <<<dim3(NTOT / LO), dim3(TPB1), 0, stream>>>(hS, bet, st, out);
}